// Round 6
// baseline (423.130 us; speedup 1.0000x reference)
//
#include <hip/hip_runtime.h>
#include <hip/hip_bf16.h>

#define NNODES 100000
#define NEDGES 3200000
#define NG     64
#define NBUCK  196          // ceil(NNODES/512) buckets of 512 dst nodes
#define PB     512          // phase-A partition blocks
#define CHUNK  ((NEDGES + PB - 1) / PB)    // 6250 edges per block
#define CAP    20480        // staging capacity per bucket (mean 16384, sigma~128)
#define NBLK4  ((NNODES + 3) / 4)          // 25000 gather blocks
#define SWZA   200                         // 25000 = 200*125 (bijective swizzle)
#define SWZB   125
#define CNTREP 32                          // cnt replicas (kills hot-line atomics)

typedef __attribute__((ext_vector_type(4))) short short4v;
typedef __attribute__((ext_vector_type(8))) short short8v;
typedef __attribute__((ext_vector_type(4))) float ffrag;

// ---------- dtype-flexible loads (flags are wave-uniform) ----------
__device__ __forceinline__ int ld_idx(const void* p, long long i, int is64) {
    if (is64) return (int)((const long long*)p)[i];
    return ((const int*)p)[i];
}
__device__ __forceinline__ float ld_f(const void* p, long long i, int isf32) {
    if (isf32) return ((const float*)p)[i];
    return __bfloat162float(((const __hip_bfloat16*)p)[i]);
}
__device__ __forceinline__ float bfbits(unsigned b) {
    return __uint_as_float(b << 16);
}
__device__ __forceinline__ unsigned short bf16b(float v) {
    __hip_bfloat16 h = __float2bfloat16(v);
    return *(unsigned short*)&h;
}
__device__ __forceinline__ void acc8w(float* acc, uint4 u, float w) {
    acc[0] = fmaf(w, bfbits(u.x & 0xffffu), acc[0]);
    acc[1] = fmaf(w, bfbits(u.x >> 16),     acc[1]);
    acc[2] = fmaf(w, bfbits(u.y & 0xffffu), acc[2]);
    acc[3] = fmaf(w, bfbits(u.y >> 16),     acc[3]);
    acc[4] = fmaf(w, bfbits(u.z & 0xffffu), acc[4]);
    acc[5] = fmaf(w, bfbits(u.z >> 16),     acc[5]);
    acc[6] = fmaf(w, bfbits(u.w & 0xffffu), acc[6]);
    acc[7] = fmaf(w, bfbits(u.w >> 16),     acc[7]);
}

// ---------- runtime dtype detection + workspace init (replaces 2 memsets) ----------
__global__ void detect_kernel(const void* x, const void* ei, const void* bat, int* flags,
                              int* gcur, float* pooled, float* cntR) {
    __shared__ int f[3];
    int t = threadIdx.x;
    if (t < 3) f[t] = 0;
    __syncthreads();
    const unsigned short* u = (const unsigned short*)x;
    int e = (u[t] >> 7) & 0xFF;
    if (e >= 0x90) atomicOr(&f[0], 1);                 // fp32-reinterpret signature
    const unsigned* w = (const unsigned*)ei;
    if (w[2 * t + 1] != 0u) atomicOr(&f[1], 1);        // odd word nonzero -> int32
    const unsigned* bw = (const unsigned*)bat;
    if (bw[50001 + 2 * t] != 0u) atomicOr(&f[2], 1);   // mid-array odd words
    __syncthreads();
    if (t == 0) { flags[0] = f[0]; flags[1] = !f[1]; flags[2] = !f[2]; }
    if (gcur) {
        gcur[t] = t * CAP;                             // bucket base cursors
        for (int i = t; i < NG * 64; i += 256) pooled[i] = 0.f;
        for (int i = t; i < CNTREP * NG; i += 256) cntR[i] = 0.f;
    }
}

// ---------- fused phase A: count + reserve + partition in ONE pass ----------
// Each block: (1) read its edge chunk once, pack into LDS, count buckets in LDS;
// (2) reserve [base, base+cnt) per bucket via global atomicAdd on gcur;
// (3) scatter LDS->staging. Staging is bucket-gapped at CAP stride; capacity
// CAP=20480 vs Binomial mean 16384, sigma 128: 32-sigma guard.
__global__ __launch_bounds__(256)
void binA_fused(const void* ei, const int* __restrict__ flags,
                int* __restrict__ gcur, unsigned* __restrict__ staging, int E) {
    __shared__ unsigned pk[CHUNK];          // packed s | (d&511)<<17
    __shared__ unsigned char bk[CHUNK];     // bucket id (0xFF = invalid)
    __shared__ int cnt[256];
    __shared__ int base[256];
    int is64 = flags[1];
    int t = threadIdx.x;
    cnt[t] = 0;
    __syncthreads();
    int beg = blockIdx.x * CHUNK;
    int end = min(E, beg + CHUNK);
    for (int i = beg + t; i < end; i += 256) {
        int s = ld_idx(ei, i, is64);
        int d = ld_idx(ei, (long long)E + i, is64);
        unsigned b = 0xFFu;
        unsigned p = 0u;
        if ((unsigned)s < (unsigned)NNODES && (unsigned)d < (unsigned)NNODES) {
            b = (unsigned)(d >> 9);
            p = (unsigned)s | ((unsigned)(d & 511) << 17);
            atomicAdd(&cnt[b], 1);
        }
        pk[i - beg] = p;
        bk[i - beg] = (unsigned char)b;
    }
    __syncthreads();
    {
        int c = cnt[t];
        base[t] = c ? atomicAdd(&gcur[t], c) : 0;
        cnt[t] = 0;                         // becomes relative cursor
    }
    __syncthreads();
    for (int i = beg + t; i < end; i += 256) {
        unsigned b = bk[i - beg];
        if (b != 0xFFu) {
            int r = atomicAdd(&cnt[b], 1);
            int pos = base[b] + r;
            if (pos < (int)((b + 1) * CAP)) staging[pos] = pk[i - beg];
        }
    }
}

// ---------- phase B: per-bucket degrees -> rs/re + dinv + COMPACT CSR fill ----------
// Input: bucket b owns staging[b*CAP, b*CAP+size_b) (bucket-gapped).
// Output: csr is COMPACT -- each block scans all NBUCK sizes (from gcur) in LDS
// to get its output base obase = sum(sizes[0..b)), so csr fits in E words.
__global__ void binB_all(const unsigned* __restrict__ staging, const int* __restrict__ gcur,
                         int* __restrict__ rs, int* __restrict__ re,
                         float* __restrict__ dinv, int* __restrict__ csr) {
    __shared__ int dcnt[512];
    __shared__ int ls[256];
    __shared__ int sizes[256];
    int b = blockIdx.x;
    int lo = b << 9;
    int t = threadIdx.x;
    // exclusive scan of all bucket sizes -> compact output base for bucket b
    int sz = 0;
    if (t < NBUCK) sz = min(gcur[t] - t * CAP, CAP);
    sizes[t] = sz;
    __syncthreads();
    for (int off = 1; off < 256; off <<= 1) {
        int p = (t >= off) ? sizes[t - off] : 0;
        __syncthreads();
        sizes[t] += p;
        __syncthreads();
    }
    int obase = (b == 0) ? 0 : sizes[b - 1];
    int msize = sizes[b] - obase;

    for (int i = t; i < 512; i += 256) dcnt[i] = 0;
    __syncthreads();
    int beg = b * CAP;                      // input (bucket-gapped)
    int end = beg + msize;
    for (int i = beg + t; i < end; i += 256)
        atomicAdd(&dcnt[staging[i] >> 17], 1);
    __syncthreads();
    int a  = dcnt[2 * t];
    int b2 = dcnt[2 * t + 1];
    int csum = a + b2;
    ls[t] = csum;
    __syncthreads();
    for (int off = 1; off < 256; off <<= 1) {
        int p = (t >= off) ? ls[t - off] : 0;
        __syncthreads();
        ls[t] += p;
        __syncthreads();
    }
    int pref = ls[t] - csum;
    int n0 = lo + 2 * t, n1 = lo + 2 * t + 1;
    if (n0 < NNODES) {
        rs[n0] = obase + pref;      re[n0] = obase + pref + a;
        dinv[n0] = rsqrtf((float)a + 1.0f);
    }
    if (n1 < NNODES) {
        rs[n1] = obase + pref + a;  re[n1] = obase + pref + a + b2;
        dinv[n1] = rsqrtf((float)b2 + 1.0f);
    }
    __syncthreads();
    dcnt[2 * t]     = obase + pref;             // compact output cursors
    dcnt[2 * t + 1] = obase + pref + a;
    __syncthreads();
    for (int i = beg + t; i < end; i += 256) {  // staging chunk L2-hot from pass 1
        unsigned u = staging[i];
        int pos = atomicAdd(&dcnt[u >> 17], 1);
        csr[pos] = (int)(u & 0x1FFFFu);
    }
}

// ---------- MFMA GEMM v3: W-only LDS, A-fragments direct from global ----------
// Single delta vs round-4 (419us, passed): the lsX staging array + its barrier
// are gone; each lane loads its A-fragment straight from global with the SAME
// battle-tested short4v-pair idiom the LDS path used. Tail-tile rows use an
// exec-masked zero-fill guard (no load at all for rows >= nrows; zero rows give
// zero outputs; stores remain guarded). W staging is byte-identical to round 4
// (scalar loop, isf32 honored for ALL XMODE -- also fixes the round-5 latent
// fp32-W2 bug). LDS 33.8 -> 16.9 KB, 2 barriers -> 1.
// Layouts (m89/m120 verified): A[m=lane&15][k=quad*8+j]; B[k=quad*8+j][n=lane&15];
// C/D row=quad*4+reg, col=lane&15.
template <int K, int XMODE>
__global__ __launch_bounds__(256)
void gemm_mfma(const void* __restrict__ X, const void* __restrict__ W,
               const int* __restrict__ flags, const float* __restrict__ dscale,
               __hip_bfloat16* __restrict__ Out, int N) {
    const int S = K + 4;                 // pad: frag b64 reads land on <=4-way banks
    __shared__ unsigned short lsWt[64 * S];   // [c][k] bf16 (W transposed)
    int isf32 = flags[0];
    // stage W transposed (round-4 exact): coalesced read, scattered LDS write
    for (int i = threadIdx.x; i < K * 64; i += 256) {
        int k = i >> 6, c = i & 63;
        unsigned short v = isf32 ? bf16b(((const float*)W)[i])
                                 : ((const unsigned short*)W)[i];
        lsWt[c * S + k] = v;
    }
    __syncthreads();

    int lane = threadIdx.x & 63;
    int wv   = threadIdx.x >> 6;        // wave owns rows [wv*16, wv*16+16)
    int m    = lane & 15;
    int quad = lane >> 4;
    int ntiles = (N + 63) >> 6;

    for (int t = blockIdx.x; t < ntiles; t += gridDim.x) {
        int row0 = t << 6;
        int nrows = min(64, N - row0);
        int rbase = wv * 16;
        bool rowok = (rbase + m) < nrows;         // exec-mask guard for tail tiles
        long long xrow = (long long)(row0 + rbase + m) * K;

        ffrag acc0 = {0.f, 0.f, 0.f, 0.f};
        ffrag acc1 = {0.f, 0.f, 0.f, 0.f};
        ffrag acc2 = {0.f, 0.f, 0.f, 0.f};
        ffrag acc3 = {0.f, 0.f, 0.f, 0.f};
#pragma unroll
        for (int ks = 0; ks < K; ks += 32) {
            short8v a = {0, 0, 0, 0, 0, 0, 0, 0};
            if (rowok) {
                if (XMODE == 0 && isf32) {
                    const float* Xf = (const float*)X + xrow + quad * 8 + ks;
                    float4 f0 = *(const float4*)Xf;
                    float4 f1 = *(const float4*)(Xf + 4);
                    a[0] = (short)bf16b(f0.x); a[1] = (short)bf16b(f0.y);
                    a[2] = (short)bf16b(f0.z); a[3] = (short)bf16b(f0.w);
                    a[4] = (short)bf16b(f1.x); a[5] = (short)bf16b(f1.y);
                    a[6] = (short)bf16b(f1.z); a[7] = (short)bf16b(f1.w);
                } else {
                    const unsigned short* Xh =
                        (const unsigned short*)X + xrow + quad * 8 + ks;
                    short4v al = *(const short4v*)Xh;
                    short4v ah = *(const short4v*)(Xh + 4);
                    a = __builtin_shufflevector(al, ah, 0, 1, 2, 3, 4, 5, 6, 7);
                }
            }
#pragma unroll
            for (int ct = 0; ct < 4; ++ct) {
                int boff = (ct * 16 + m) * S + quad * 8 + ks;
                short4v bl = *(const short4v*)&lsWt[boff];
                short4v bh = *(const short4v*)&lsWt[boff + 4];
                short8v b = __builtin_shufflevector(bl, bh, 0, 1, 2, 3, 4, 5, 6, 7);
                if (ct == 0) acc0 = __builtin_amdgcn_mfma_f32_16x16x32_bf16(a, b, acc0, 0, 0, 0);
                if (ct == 1) acc1 = __builtin_amdgcn_mfma_f32_16x16x32_bf16(a, b, acc1, 0, 0, 0);
                if (ct == 2) acc2 = __builtin_amdgcn_mfma_f32_16x16x32_bf16(a, b, acc2, 0, 0, 0);
                if (ct == 3) acc3 = __builtin_amdgcn_mfma_f32_16x16x32_bf16(a, b, acc3, 0, 0, 0);
            }
        }
        long long ob = (long long)row0 * 64;
#pragma unroll
        for (int r = 0; r < 4; ++r) {
            int row = rbase + quad * 4 + r;
            if (row < nrows) {
                float ds = dscale ? dscale[row0 + row] : 1.f;
                long long rb = ob + (long long)row * 64 + m;
                Out[rb]      = __float2bfloat16(acc0[r] * ds);
                Out[rb + 16] = __float2bfloat16(acc1[r] * ds);
                Out[rb + 32] = __float2bfloat16(acc2[r] * ds);
                Out[rb + 48] = __float2bfloat16(acc3[r] * ds);
            }
        }
    }
}

// ---------- fp32 VALU GEMM (fallback path only; round-7 proven) ----------
template <int K, int XMODE>
__global__ __launch_bounds__(256)
void gemm_tile(const void* __restrict__ X, const void* __restrict__ W,
               const int* __restrict__ flags, const float* __restrict__ dscale,
               float* __restrict__ Out, int N) {
    __shared__ float lsW[K * 64];
    __shared__ float lsX[64 * K];
    int isf32 = flags[0];
    for (int i = threadIdx.x; i < K * 64; i += 256) lsW[i] = ld_f(W, i, isf32);
    int c  = threadIdx.x & 63;
    int wv = threadIdx.x >> 6;
    int ntiles = (N + 63) >> 6;
    for (int t = blockIdx.x; t < ntiles; t += gridDim.x) {
        int row0 = t << 6;
        int nrows = min(64, N - row0);
        int total = nrows * K;
        __syncthreads();
        if (XMODE == 1 || (XMODE == 0 && isf32)) {
            const float* Xb = (const float*)X + (long long)row0 * K;
            for (int i = threadIdx.x; i < total; i += 256) lsX[i] = Xb[i];
        } else {
            const unsigned short* Xb = (const unsigned short*)X + (long long)row0 * K;
            for (int i = threadIdx.x; i < total; i += 256) lsX[i] = bfbits((unsigned)Xb[i]);
        }
        __syncthreads();
        int rbase = wv * 16;
        float acc[16];
#pragma unroll
        for (int r = 0; r < 16; ++r) acc[r] = 0.f;
#pragma unroll 1
        for (int kc = 0; kc < K; kc += 8) {
            float w0 = lsW[(kc + 0) * 64 + c], w1 = lsW[(kc + 1) * 64 + c];
            float w2 = lsW[(kc + 2) * 64 + c], w3 = lsW[(kc + 3) * 64 + c];
            float w4 = lsW[(kc + 4) * 64 + c], w5 = lsW[(kc + 5) * 64 + c];
            float w6 = lsW[(kc + 6) * 64 + c], w7 = lsW[(kc + 7) * 64 + c];
#pragma unroll
            for (int r = 0; r < 16; ++r) {
                const float4* xp = (const float4*)&lsX[(rbase + r) * K + kc];
                float4 xa = xp[0], xb = xp[1];
                acc[r] += xa.x * w0 + xa.y * w1 + xa.z * w2 + xa.w * w3
                        + xb.x * w4 + xb.y * w5 + xb.z * w6 + xb.w * w7;
            }
        }
        long long ob = (long long)row0 * 64;
#pragma unroll
        for (int r = 0; r < 16; ++r) {
            int rr = rbase + r;
            if (rr < nrows) {
                float v = acc[r];
                if (dscale) v *= dscale[row0 + rr];
                Out[ob + (long long)rr * 64 + c] = v;
            }
        }
    }
}

// ---------- vectorized CSR gather, 4/8-deep pipelined, clamped loads ----------
// POOL=0: write bf16 Hout (optional out_scale).
// POOL=1: fused global-mean-pool. Block->node mapping is swizzled (bijective
// 200x125) so concurrently-resident blocks span ALL graphs (round-1 lesson).
template <int POOL>
__global__ __launch_bounds__(256)
void gather_v(const __hip_bfloat16* __restrict__ Hs,
              const int* __restrict__ rs,
              const int* __restrict__ re,
              const int* __restrict__ csr_src,
              const float* __restrict__ dinv,
              const void* bias, const int* __restrict__ flags,
              const float* __restrict__ out_scale,
              __hip_bfloat16* __restrict__ Hout,
              const void* batch, float* __restrict__ pooled,
              float* __restrict__ cntR, int N) {
    int isf32 = flags[0];
    int lane = threadIdx.x & 63;
    int e = lane >> 3;
    int f = lane & 7;
    int sub = threadIdx.x >> 6;
    int bid = blockIdx.x;
    int sb = (POOL == 1) ? ((bid % SWZA) * SWZB + bid / SWZA) : bid;
    int n = sb * 4 + sub;
    bool valid = n < N;
    if (POOL == 0 && !valid) return;

    int beg = 0, end = 0;
    if (valid) { beg = rs[n]; end = re[n]; }

    float acc[8];
#pragma unroll
    for (int j = 0; j < 8; ++j) acc[j] = 0.f;

    // 64 edges/iter with a wave-uniform half-guard: 4 row gathers in flight for
    // deg<=32 (54% of nodes), 8 for deg>32. Weights zero out clamped tails.
    for (int i = beg; i < end; i += 64) {
        int last = end - 1;
        int i0 = i + e;
        int s0 = csr_src[min(i0,      last)];
        int s1 = csr_src[min(i0 + 8,  last)];
        int s2 = csr_src[min(i0 + 16, last)];
        int s3 = csr_src[min(i0 + 24, last)];
        float w0 = (i0      < end) ? 1.f : 0.f;
        float w1 = (i0 + 8  < end) ? 1.f : 0.f;
        float w2 = (i0 + 16 < end) ? 1.f : 0.f;
        float w3 = (i0 + 24 < end) ? 1.f : 0.f;
        uint4 u0 = *((const uint4*)(Hs + ((long long)s0 << 6)) + f);
        uint4 u1 = *((const uint4*)(Hs + ((long long)s1 << 6)) + f);
        uint4 u2 = *((const uint4*)(Hs + ((long long)s2 << 6)) + f);
        uint4 u3 = *((const uint4*)(Hs + ((long long)s3 << 6)) + f);
        acc8w(acc, u0, w0);
        acc8w(acc, u1, w1);
        acc8w(acc, u2, w2);
        acc8w(acc, u3, w3);
        if (i + 32 < end) {                 // wave-uniform branch
            int i1 = i0 + 32;
            int s4 = csr_src[min(i1,      last)];
            int s5 = csr_src[min(i1 + 8,  last)];
            int s6 = csr_src[min(i1 + 16, last)];
            int s7 = csr_src[min(i1 + 24, last)];
            float w4 = (i1      < end) ? 1.f : 0.f;
            float w5 = (i1 + 8  < end) ? 1.f : 0.f;
            float w6 = (i1 + 16 < end) ? 1.f : 0.f;
            float w7 = (i1 + 24 < end) ? 1.f : 0.f;
            uint4 u4 = *((const uint4*)(Hs + ((long long)s4 << 6)) + f);
            uint4 u5 = *((const uint4*)(Hs + ((long long)s5 << 6)) + f);
            uint4 u6 = *((const uint4*)(Hs + ((long long)s6 << 6)) + f);
            uint4 u7 = *((const uint4*)(Hs + ((long long)s7 << 6)) + f);
            acc8w(acc, u4, w4);
            acc8w(acc, u5, w5);
            acc8w(acc, u6, w6);
            acc8w(acc, u7, w7);
        }
    }
#pragma unroll
    for (int j = 0; j < 8; ++j) {
        acc[j] += __shfl_xor(acc[j], 8);
        acc[j] += __shfl_xor(acc[j], 16);
        acc[j] += __shfl_xor(acc[j], 32);
    }
    float self[8];
#pragma unroll
    for (int j = 0; j < 8; ++j) self[j] = 0.f;
    if (valid) {
        const uint4* sp = (const uint4*)(Hs + ((long long)n << 6)) + f;
        uint4 su = *sp;
        self[0] = bfbits(su.x & 0xffffu); self[1] = bfbits(su.x >> 16);
        self[2] = bfbits(su.y & 0xffffu); self[3] = bfbits(su.y >> 16);
        self[4] = bfbits(su.z & 0xffffu); self[5] = bfbits(su.z >> 16);
        self[6] = bfbits(su.w & 0xffffu); self[7] = bfbits(su.w >> 16);
    }
    float dn = valid ? dinv[n] : 0.f;

    if constexpr (POOL == 0) {
        float osc = out_scale ? out_scale[n] : 1.f;
        if (e == 0) {
            unsigned short h[8];
#pragma unroll
            for (int j = 0; j < 8; ++j) {
                float v = (acc[j] + self[j]) * dn + ld_f(bias, 8 * f + j, isf32);
                float r = v > 0.f ? v : 0.f;
                h[j] = bf16b(r * osc);
            }
            uint4 o;
            o.x = (unsigned)h[0] | ((unsigned)h[1] << 16);
            o.y = (unsigned)h[2] | ((unsigned)h[3] << 16);
            o.z = (unsigned)h[4] | ((unsigned)h[5] << 16);
            o.w = (unsigned)h[6] | ((unsigned)h[7] << 16);
            *((uint4*)(Hout + ((long long)n << 6)) + f) = o;
        }
    } else {
        __shared__ float pbuf[4][64];
        __shared__ int pg[4];
        if (valid && e == 0) {
#pragma unroll
            for (int j = 0; j < 8; ++j) {
                float v = (acc[j] + self[j]) * dn + ld_f(bias, 8 * f + j, isf32);
                pbuf[sub][8 * f + j] = v > 0.f ? v : 0.f;
            }
        }
        if (lane == 0) {
            int g = -1;
            if (valid) {
                g = ld_idx(batch, n, flags[2]);
                if ((unsigned)g >= (unsigned)NG) g = -1;
            }
            pg[sub] = g;
        }
        __syncthreads();
        int c = threadIdx.x;
        if (c < 64) {
            // merge equal-graph runs: common case is 64 atomics per block,
            // spread across all graphs thanks to the block swizzle.
            float run = 0.f;
            int gcur2 = pg[0];
#pragma unroll
            for (int r = 0; r < 4; ++r) {
                int g = pg[r];
                if (g != gcur2) {
                    if (gcur2 >= 0 && run != 0.f) atomicAdd(&pooled[gcur2 * 64 + c], run);
                    run = 0.f;
                    gcur2 = g;
                }
                if (g >= 0) run += pbuf[r][c];
            }
            if (gcur2 >= 0 && run != 0.f) atomicAdd(&pooled[gcur2 * 64 + c], run);
        } else if (c == 64) {
            // run-merged node counts into a per-block replica (32 replicas)
            float* myc = cntR + (bid & (CNTREP - 1)) * NG;
            int run = 0;
            int gcur2 = pg[0];
#pragma unroll
            for (int r = 0; r < 4; ++r) {
                int g = pg[r];
                if (g != gcur2) {
                    if (gcur2 >= 0 && run) atomicAdd(&myc[gcur2], (float)run);
                    run = 0;
                    gcur2 = g;
                }
                if (g >= 0) run++;
            }
            if (gcur2 >= 0 && run) atomicAdd(&myc[gcur2], (float)run);
        }
    }
}

// ---------- final (cnt held in nrep replicas) ----------
__global__ void final_kernel(const float* __restrict__ pooled, const float* __restrict__ cntR,
                             int nrep, const void* lw, const void* lb,
                             const int* __restrict__ flags, void* out) {
    int isf32 = flags[0];
    int g = threadIdx.x;
    if (g >= NG) return;
    float cv = 0.f;
    for (int r = 0; r < nrep; ++r) cv += cntR[r * NG + g];
    float inv = 1.0f / fmaxf(cv, 1.0f);
    float logits[10];
    for (int c = 0; c < 10; ++c) logits[c] = ld_f(lb, c, isf32);
    for (int k = 0; k < 64; ++k) {
        float m = pooled[g * 64 + k] * inv;
        for (int c = 0; c < 10; ++c)
            logits[c] += m * ld_f(lw, k * 10 + c, isf32);
    }
    float mx = logits[0];
    for (int c = 1; c < 10; ++c) mx = fmaxf(mx, logits[c]);
    float se = 0.f;
    for (int c = 0; c < 10; ++c) se += __expf(logits[c] - mx);
    float lse = mx + __logf(se);
    if (isf32) {
        float* o = (float*)out;
        for (int c = 0; c < 10; ++c) o[g * 10 + c] = logits[c] - lse;
    } else {
        __hip_bfloat16* o = (__hip_bfloat16*)out;
        for (int c = 0; c < 10; ++c) o[g * 10 + c] = __float2bfloat16(logits[c] - lse);
    }
}

// ---------- fallback pipeline kernels (round-2 proven, atomic scatter, fp32) ----------
__global__ void count_kernel(const void* ei, const int* __restrict__ flags,
                             int* __restrict__ deg, int E) {
    int is64 = flags[1];
    int i = blockIdx.x * blockDim.x + threadIdx.x;
    int stride = gridDim.x * blockDim.x;
    for (; i < E; i += stride) {
        int d = ld_idx(ei, (long long)E + i, is64);
        if ((unsigned)d < (unsigned)NNODES) atomicAdd(&deg[d], 1);
    }
}

__global__ void dinv_kernel(const int* __restrict__ deg, float* __restrict__ dinv, int N) {
    int i = blockIdx.x * blockDim.x + threadIdx.x;
    if (i < N) dinv[i] = rsqrtf((float)deg[i] + 1.0f);
}

__global__ void scatter_kernel(const float* __restrict__ H, const void* ei,
                               const int* __restrict__ flags,
                               const float* __restrict__ dinv,
                               float* __restrict__ agg, int E) {
    int is64 = flags[1];
    int lane = threadIdx.x & 63;
    int e = blockIdx.x * 4 + (threadIdx.x >> 6);
    if (e >= E) return;
    int s = ld_idx(ei, e, is64);
    int d = ld_idx(ei, (long long)E + e, is64);
    if ((unsigned)s >= (unsigned)NNODES || (unsigned)d >= (unsigned)NNODES) return;
    float nrm = dinv[s] * dinv[d];
    float v = H[(long long)s * 64 + lane] * nrm;
    atomicAdd(&agg[(long long)d * 64 + lane], v);
}

__global__ void relu_bias_kernel(float* __restrict__ H, const float* __restrict__ agg,
                                 const float* __restrict__ dinv, const void* b,
                                 const int* __restrict__ flags, int N) {
    int isf32 = flags[0];
    long long idx = (long long)blockIdx.x * blockDim.x + threadIdx.x;
    if (idx >= (long long)N * 64) return;
    int n = (int)(idx >> 6);
    int c = (int)(idx & 63);
    float dv = dinv[n];
    float v = agg[idx] + H[idx] * dv * dv + ld_f(b, c, isf32);
    H[idx] = v > 0.f ? v : 0.f;
}

__global__ void pool_fb_kernel(const float* __restrict__ agg, const float* __restrict__ Hg,
                               const float* __restrict__ dinv, const void* b,
                               const void* batch, const int* __restrict__ flags,
                               float* __restrict__ pooled, float* __restrict__ cnt, int N) {
    __shared__ float part[NG * 64];
    __shared__ float scnt[NG];
    int isf32 = flags[0];
    int b64   = flags[2];
    int tid = threadIdx.x;
    for (int i = tid; i < NG * 64; i += blockDim.x) part[i] = 0.f;
    if (tid < NG) scnt[tid] = 0.f;
    __syncthreads();
    int c = tid & 63;
    int sub = tid >> 6;
    float bc = ld_f(b, c, isf32);
    for (int n = blockIdx.x * 4 + sub; n < N; n += gridDim.x * 4) {
        int g = ld_idx(batch, n, b64);
        if ((unsigned)g >= (unsigned)NG) continue;
        float dv = dinv[n];
        float v = agg[(long long)n * 64 + c] + Hg[(long long)n * 64 + c] * dv * dv + bc;
        v = v > 0.f ? v : 0.f;
        atomicAdd(&part[g * 64 + c], v);
        if (c == 0) atomicAdd(&scnt[g], 1.0f);
    }
    __syncthreads();
    for (int i = tid; i < NG * 64; i += blockDim.x) {
        float v = part[i];
        if (v != 0.f) atomicAdd(&pooled[i], v);
    }
    if (tid < NG && scnt[tid] != 0.f) atomicAdd(&cnt[tid], scnt[tid]);
}

__global__ void zero_out_kernel(unsigned short* out, int n16) {
    int i = blockIdx.x * blockDim.x + threadIdx.x;
    if (i < n16) out[i] = 0;
}

extern "C" void kernel_launch(void* const* d_in, const int* in_sizes, int n_in,
                              void* d_out, int out_size, void* d_ws, size_t ws_size,
                              hipStream_t stream) {
    const void* x   = d_in[0];
    const void* ei  = d_in[1];   // [2, E] flat: src then dst
    const void* bat = d_in[2];
    const void* W1  = d_in[3];
    const void* b1  = d_in[4];
    const void* W2  = d_in[5];
    const void* b2  = d_in[6];
    const void* lw  = d_in[7];
    const void* lb  = d_in[8];

    const int N = NNODES, E = NEDGES;
    int* ws = (int*)d_ws;
    const int NT = (N + 63) / 64;    // gemm tiles

    // ---- CSR-path layout (words). staging aliases bufA (dead before GEMM1). ----
    const long long o_flags = 0;                          // 16
    const long long o_re    = 16;                         // N (per-node CSR end)
    const long long o_dinv  = 16 + (long long)N;          // N
    const long long o_rs    = 16 + 2LL * N;               // N+1 (per-node CSR start)
    const long long o_gcur  = 300032;                     // 256 bucket cursors
    const long long o_cntR  = 300288;                     // CNTREP*NG = 2048
    const long long o_pool  = 350272;                     // NG*64
    const long long o_cnt   = o_pool + NG * 64;           // NG (fallback cnt)
    const long long o_csr   = 354432;                     // E words (COMPACT csr)
    const long long o_bufA  = o_csr + E;                  // N*64 words (bf16 uses half)
    const long long o_bufB  = o_bufA + (long long)N * 64; // N*64 words
    const size_t need_csr = (size_t)(o_bufB + (long long)N * 64) * 4;   // ~65.4 MB

    // staging (bucket-gapped, CAP*NBUCK = 4,014,080 words) aliases bufA+bufB
    // (12.8M words) -- both dead until GEMM1 runs.

    // ---- fallback layout ----
    const size_t need_fb = (size_t)(204800 + 2LL * N * 64) * 4;

    if (ws_size >= need_csr) {
        int*      flags   = ws + o_flags;
        int*      re      = ws + o_re;
        float*    dinv    = (float*)(ws + o_dinv);
        int*      rs      = ws + o_rs;
        int*      gcur    = ws + o_gcur;
        float*    cntR    = (float*)(ws + o_cntR);
        float*    pooled  = (float*)(ws + o_pool);
        int*      csr     = ws + o_csr;
        unsigned* staging = (unsigned*)(ws + o_bufA);     // alias: dead before GEMM1
        __hip_bfloat16* hA = (__hip_bfloat16*)(ws + o_bufA);
        __hip_bfloat16* hB = (__hip_bfloat16*)(ws + o_bufB);

        // detect dtypes + init cursors/pooled/cnt (no memset launches)
        detect_kernel<<<1, 256, 0, stream>>>(x, ei, bat, flags, gcur, pooled, cntR);

        // 2-kernel CSR build: fused count+reserve+partition, then per-bucket fill
        binA_fused<<<PB, 256, 0, stream>>>(ei, flags, gcur, staging, E);
        binB_all<<<NBUCK, 256, 0, stream>>>(staging, gcur, rs, re, dinv, csr);

        // layer 1: MFMA gemm1 -> bf16 dinv*(x@W1); gather1 -> bf16 dinv*relu(...)
        gemm_mfma<128, 0><<<NT, 256, 0, stream>>>(x, W1, flags, dinv, hA, N);
        gather_v<0><<<NBLK4, 256, 0, stream>>>(hA, rs, re, csr, dinv, b1, flags, dinv, hB,
                                               nullptr, nullptr, nullptr, N);
        // layer 2: MFMA gemm2 bf16 -> bf16; gather2 fused with global mean pool
        gemm_mfma<64, 2><<<NT, 256, 0, stream>>>(hB, W2, flags, nullptr, hA, N);
        gather_v<1><<<NBLK4, 256, 0, stream>>>(hA, rs, re, csr, dinv, b2, flags, nullptr,
                                               nullptr, bat, pooled, cntR, N);

        final_kernel<<<1, 64, 0, stream>>>(pooled, cntR, CNTREP, lw, lb, flags, d_out);
    } else if (ws_size >= need_fb) {
        int*   flags  = ws;
        int*   deg    = ws + 16;
        float* dinv   = (float*)(ws + 16 + N);
        float* pooled = (float*)(ws + 16 + 2LL * N);
        float* cnt    = pooled + NG * 64;
        float* bufA   = (float*)(ws + 204800);
        float* bufB   = bufA + (long long)N * 64;

        detect_kernel<<<1, 256, 0, stream>>>(x, ei, bat, flags, nullptr, nullptr, nullptr);
        hipMemsetAsync(deg, 0, N * sizeof(int), stream);
        hipMemsetAsync(pooled, 0, (NG * 64 + NG) * sizeof(float), stream);

        count_kernel<<<2048, 256, 0, stream>>>(ei, flags, deg, E);
        dinv_kernel<<<(N + 255) / 256, 256, 0, stream>>>(deg, dinv, N);

        gemm_tile<128, 0><<<NT, 256, 0, stream>>>(x, W1, flags, nullptr, bufA, N);
        hipMemsetAsync(bufB, 0, (size_t)N * 64 * sizeof(float), stream);
        scatter_kernel<<<(E + 3) / 4, 256, 0, stream>>>(bufA, ei, flags, dinv, bufB, E);
        relu_bias_kernel<<<((long long)N * 64 + 255) / 256, 256, 0, stream>>>(bufA, bufB, dinv, b1, flags, N);

        gemm_tile<64, 1><<<NT, 256, 0, stream>>>(bufA, W2, flags, nullptr, bufB, N);
        hipMemsetAsync(bufA, 0, (size_t)N * 64 * sizeof(float), stream);
        scatter_kernel<<<(E + 3) / 4, 256, 0, stream>>>(bufB, ei, flags, dinv, bufA, E);

        pool_fb_kernel<<<512, 256, 0, stream>>>(bufA, bufB, dinv, b2, bat, flags, pooled, cnt, N);
        final_kernel<<<1, 64, 0, stream>>>(pooled, cnt, 1, lw, lb, flags, d_out);
    } else {
        zero_out_kernel<<<(out_size * 2 + 255) / 256, 256, 0, stream>>>(
            (unsigned short*)d_out, out_size);
    }
}

// Round 7
// 410.649 us; speedup vs baseline: 1.0304x; 1.0304x over previous
//
#include <hip/hip_runtime.h>
#include <hip/hip_bf16.h>

#define NNODES 100000
#define NEDGES 3200000
#define NG     64
#define NBUCK  196          // ceil(NNODES/512) buckets of 512 dst nodes
#define PB     512          // phase-A partition blocks
#define CHUNK  ((NEDGES + PB - 1) / PB)    // 6250 edges per block
#define CAP    20480        // staging capacity per bucket (mean 16384, sigma~128)
#define NBLK4  ((NNODES + 3) / 4)          // 25000 gather blocks
#define SWZA   200                         // 25000 = 200*125 (bijective swizzle)
#define SWZB   125
#define CNTREP 32                          // cnt replicas (kills hot-line atomics)

typedef __attribute__((ext_vector_type(4))) short short4v;
typedef __attribute__((ext_vector_type(8))) short short8v;
typedef __attribute__((ext_vector_type(4))) float ffrag;

// ---------- dtype-flexible loads (flags are wave-uniform) ----------
__device__ __forceinline__ int ld_idx(const void* p, long long i, int is64) {
    if (is64) return (int)((const long long*)p)[i];
    return ((const int*)p)[i];
}
__device__ __forceinline__ float ld_f(const void* p, long long i, int isf32) {
    if (isf32) return ((const float*)p)[i];
    return __bfloat162float(((const __hip_bfloat16*)p)[i]);
}
__device__ __forceinline__ float bfbits(unsigned b) {
    return __uint_as_float(b << 16);
}
__device__ __forceinline__ unsigned short bf16b(float v) {
    __hip_bfloat16 h = __float2bfloat16(v);
    return *(unsigned short*)&h;
}
// bit-exact cheap unpack: (u&0xffff)<<16 == u<<16 ; (u>>16)<<16 == u&0xffff0000
__device__ __forceinline__ void acc8w(float* acc, uint4 u, float w) {
    acc[0] = fmaf(w, __uint_as_float(u.x << 16),        acc[0]);
    acc[1] = fmaf(w, __uint_as_float(u.x & 0xffff0000u), acc[1]);
    acc[2] = fmaf(w, __uint_as_float(u.y << 16),        acc[2]);
    acc[3] = fmaf(w, __uint_as_float(u.y & 0xffff0000u), acc[3]);
    acc[4] = fmaf(w, __uint_as_float(u.z << 16),        acc[4]);
    acc[5] = fmaf(w, __uint_as_float(u.z & 0xffff0000u), acc[5]);
    acc[6] = fmaf(w, __uint_as_float(u.w << 16),        acc[6]);
    acc[7] = fmaf(w, __uint_as_float(u.w & 0xffff0000u), acc[7]);
}

// ---------- runtime dtype detection + workspace init (replaces 2 memsets) ----------
__global__ void detect_kernel(const void* x, const void* ei, const void* bat, int* flags,
                              int* gcur, float* pooled, float* cntR) {
    __shared__ int f[3];
    int t = threadIdx.x;
    if (t < 3) f[t] = 0;
    __syncthreads();
    const unsigned short* u = (const unsigned short*)x;
    int e = (u[t] >> 7) & 0xFF;
    if (e >= 0x90) atomicOr(&f[0], 1);                 // fp32-reinterpret signature
    const unsigned* w = (const unsigned*)ei;
    if (w[2 * t + 1] != 0u) atomicOr(&f[1], 1);        // odd word nonzero -> int32
    const unsigned* bw = (const unsigned*)bat;
    if (bw[50001 + 2 * t] != 0u) atomicOr(&f[2], 1);   // mid-array odd words
    __syncthreads();
    if (t == 0) { flags[0] = f[0]; flags[1] = !f[1]; flags[2] = !f[2]; }
    if (gcur) {
        gcur[t] = t * CAP;                             // bucket base cursors
        for (int i = t; i < NG * 64; i += 256) pooled[i] = 0.f;
        for (int i = t; i < CNTREP * NG; i += 256) cntR[i] = 0.f;
    }
}

// ---------- fused phase A: count + reserve + partition in ONE pass ----------
// Round-7: edge loads vectorized 2-wide (longlong2 / int2) -- halves the load
// instruction count on the 51 MB edge read. Scalar fallback for an odd tail.
// Each block: (1) read chunk, pack into LDS, count buckets in LDS; (2) reserve
// [base, base+cnt) per bucket via global atomicAdd on gcur; (3) scatter
// LDS->staging (bucket-gapped at CAP stride; 32-sigma capacity guard).
__global__ __launch_bounds__(256)
void binA_fused(const void* ei, const int* __restrict__ flags,
                int* __restrict__ gcur, unsigned* __restrict__ staging, int E) {
    __shared__ unsigned pk[CHUNK];          // packed s | (d&511)<<17
    __shared__ unsigned char bk[CHUNK];     // bucket id (0xFF = invalid)
    __shared__ int cnt[256];
    __shared__ int base[256];
    int is64 = flags[1];
    int t = threadIdx.x;
    cnt[t] = 0;
    __syncthreads();
    int beg = blockIdx.x * CHUNK;
    int end = min(E, beg + CHUNK);
    for (int i = beg + 2 * t; i < end; i += 512) {
        int s0, d0, s1 = -1, d1 = -1;
        bool pair = (i + 1 < end);
        if (pair) {
            if (is64) {
                longlong2 sv = *(const longlong2*)((const long long*)ei + i);
                longlong2 dv = *(const longlong2*)((const long long*)ei + E + i);
                s0 = (int)sv.x; d0 = (int)dv.x;
                s1 = (int)sv.y; d1 = (int)dv.y;
            } else {
                int2 sv = *(const int2*)((const int*)ei + i);
                int2 dv = *(const int2*)((const int*)ei + E + i);
                s0 = sv.x; d0 = dv.x;
                s1 = sv.y; d1 = dv.y;
            }
        } else {
            s0 = ld_idx(ei, i, is64);
            d0 = ld_idx(ei, (long long)E + i, is64);
        }
        {
            unsigned b = 0xFFu, p = 0u;
            if ((unsigned)s0 < (unsigned)NNODES && (unsigned)d0 < (unsigned)NNODES) {
                b = (unsigned)(d0 >> 9);
                p = (unsigned)s0 | ((unsigned)(d0 & 511) << 17);
                atomicAdd(&cnt[b], 1);
            }
            pk[i - beg] = p;
            bk[i - beg] = (unsigned char)b;
        }
        if (pair) {
            unsigned b = 0xFFu, p = 0u;
            if ((unsigned)s1 < (unsigned)NNODES && (unsigned)d1 < (unsigned)NNODES) {
                b = (unsigned)(d1 >> 9);
                p = (unsigned)s1 | ((unsigned)(d1 & 511) << 17);
                atomicAdd(&cnt[b], 1);
            }
            pk[i + 1 - beg] = p;
            bk[i + 1 - beg] = (unsigned char)b;
        }
    }
    __syncthreads();
    {
        int c = cnt[t];
        base[t] = c ? atomicAdd(&gcur[t], c) : 0;
        cnt[t] = 0;                         // becomes relative cursor
    }
    __syncthreads();
    for (int i = beg + t; i < end; i += 256) {
        unsigned b = bk[i - beg];
        if (b != 0xFFu) {
            int r = atomicAdd(&cnt[b], 1);
            int pos = base[b] + r;
            if (pos < (int)((b + 1) * CAP)) staging[pos] = pk[i - beg];
        }
    }
}

// ---------- phase B: per-bucket degrees -> rs/re + dinv + COMPACT CSR fill ----------
// Input: bucket b owns staging[b*CAP, b*CAP+size_b) (bucket-gapped).
// Output: csr is COMPACT -- each block scans all NBUCK sizes (from gcur) in LDS
// to get its output base obase = sum(sizes[0..b)), so csr fits in E words.
__global__ void binB_all(const unsigned* __restrict__ staging, const int* __restrict__ gcur,
                         int* __restrict__ rs, int* __restrict__ re,
                         float* __restrict__ dinv, int* __restrict__ csr) {
    __shared__ int dcnt[512];
    __shared__ int ls[256];
    __shared__ int sizes[256];
    int b = blockIdx.x;
    int lo = b << 9;
    int t = threadIdx.x;
    // exclusive scan of all bucket sizes -> compact output base for bucket b
    int sz = 0;
    if (t < NBUCK) sz = min(gcur[t] - t * CAP, CAP);
    sizes[t] = sz;
    __syncthreads();
    for (int off = 1; off < 256; off <<= 1) {
        int p = (t >= off) ? sizes[t - off] : 0;
        __syncthreads();
        sizes[t] += p;
        __syncthreads();
    }
    int obase = (b == 0) ? 0 : sizes[b - 1];
    int msize = sizes[b] - obase;

    for (int i = t; i < 512; i += 256) dcnt[i] = 0;
    __syncthreads();
    int beg = b * CAP;                      // input (bucket-gapped)
    int end = beg + msize;
    for (int i = beg + t; i < end; i += 256)
        atomicAdd(&dcnt[staging[i] >> 17], 1);
    __syncthreads();
    int a  = dcnt[2 * t];
    int b2 = dcnt[2 * t + 1];
    int csum = a + b2;
    ls[t] = csum;
    __syncthreads();
    for (int off = 1; off < 256; off <<= 1) {
        int p = (t >= off) ? ls[t - off] : 0;
        __syncthreads();
        ls[t] += p;
        __syncthreads();
    }
    int pref = ls[t] - csum;
    int n0 = lo + 2 * t, n1 = lo + 2 * t + 1;
    if (n0 < NNODES) {
        rs[n0] = obase + pref;      re[n0] = obase + pref + a;
        dinv[n0] = rsqrtf((float)a + 1.0f);
    }
    if (n1 < NNODES) {
        rs[n1] = obase + pref + a;  re[n1] = obase + pref + a + b2;
        dinv[n1] = rsqrtf((float)b2 + 1.0f);
    }
    __syncthreads();
    dcnt[2 * t]     = obase + pref;             // compact output cursors
    dcnt[2 * t + 1] = obase + pref + a;
    __syncthreads();
    for (int i = beg + t; i < end; i += 256) {  // staging chunk L2-hot from pass 1
        unsigned u = staging[i];
        int pos = atomicAdd(&dcnt[u >> 17], 1);
        csr[pos] = (int)(u & 0x1FFFFu);
    }
}

// ---------- MFMA GEMM v3: W-only LDS, A-fragments direct from global ----------
// (round-6, neutral vs round-4 but keeps LDS at 16.9 KB and one barrier)
// Layouts (m89/m120 verified): A[m=lane&15][k=quad*8+j]; B[k=quad*8+j][n=lane&15];
// C/D row=quad*4+reg, col=lane&15.
template <int K, int XMODE>
__global__ __launch_bounds__(256)
void gemm_mfma(const void* __restrict__ X, const void* __restrict__ W,
               const int* __restrict__ flags, const float* __restrict__ dscale,
               __hip_bfloat16* __restrict__ Out, int N) {
    const int S = K + 4;                 // pad: frag b64 reads land on <=4-way banks
    __shared__ unsigned short lsWt[64 * S];   // [c][k] bf16 (W transposed)
    int isf32 = flags[0];
    // stage W transposed: coalesced read, scattered LDS write
    for (int i = threadIdx.x; i < K * 64; i += 256) {
        int k = i >> 6, c = i & 63;
        unsigned short v = isf32 ? bf16b(((const float*)W)[i])
                                 : ((const unsigned short*)W)[i];
        lsWt[c * S + k] = v;
    }
    __syncthreads();

    int lane = threadIdx.x & 63;
    int wv   = threadIdx.x >> 6;        // wave owns rows [wv*16, wv*16+16)
    int m    = lane & 15;
    int quad = lane >> 4;
    int ntiles = (N + 63) >> 6;

    for (int t = blockIdx.x; t < ntiles; t += gridDim.x) {
        int row0 = t << 6;
        int nrows = min(64, N - row0);
        int rbase = wv * 16;
        bool rowok = (rbase + m) < nrows;         // exec-mask guard for tail tiles
        long long xrow = (long long)(row0 + rbase + m) * K;

        ffrag acc0 = {0.f, 0.f, 0.f, 0.f};
        ffrag acc1 = {0.f, 0.f, 0.f, 0.f};
        ffrag acc2 = {0.f, 0.f, 0.f, 0.f};
        ffrag acc3 = {0.f, 0.f, 0.f, 0.f};
#pragma unroll
        for (int ks = 0; ks < K; ks += 32) {
            short8v a = {0, 0, 0, 0, 0, 0, 0, 0};
            if (rowok) {
                if (XMODE == 0 && isf32) {
                    const float* Xf = (const float*)X + xrow + quad * 8 + ks;
                    float4 f0 = *(const float4*)Xf;
                    float4 f1 = *(const float4*)(Xf + 4);
                    a[0] = (short)bf16b(f0.x); a[1] = (short)bf16b(f0.y);
                    a[2] = (short)bf16b(f0.z); a[3] = (short)bf16b(f0.w);
                    a[4] = (short)bf16b(f1.x); a[5] = (short)bf16b(f1.y);
                    a[6] = (short)bf16b(f1.z); a[7] = (short)bf16b(f1.w);
                } else {
                    const unsigned short* Xh =
                        (const unsigned short*)X + xrow + quad * 8 + ks;
                    short4v al = *(const short4v*)Xh;
                    short4v ah = *(const short4v*)(Xh + 4);
                    a = __builtin_shufflevector(al, ah, 0, 1, 2, 3, 4, 5, 6, 7);
                }
            }
#pragma unroll
            for (int ct = 0; ct < 4; ++ct) {
                int boff = (ct * 16 + m) * S + quad * 8 + ks;
                short4v bl = *(const short4v*)&lsWt[boff];
                short4v bh = *(const short4v*)&lsWt[boff + 4];
                short8v b = __builtin_shufflevector(bl, bh, 0, 1, 2, 3, 4, 5, 6, 7);
                if (ct == 0) acc0 = __builtin_amdgcn_mfma_f32_16x16x32_bf16(a, b, acc0, 0, 0, 0);
                if (ct == 1) acc1 = __builtin_amdgcn_mfma_f32_16x16x32_bf16(a, b, acc1, 0, 0, 0);
                if (ct == 2) acc2 = __builtin_amdgcn_mfma_f32_16x16x32_bf16(a, b, acc2, 0, 0, 0);
                if (ct == 3) acc3 = __builtin_amdgcn_mfma_f32_16x16x32_bf16(a, b, acc3, 0, 0, 0);
            }
        }
        long long ob = (long long)row0 * 64;
#pragma unroll
        for (int r = 0; r < 4; ++r) {
            int row = rbase + quad * 4 + r;
            if (row < nrows) {
                float ds = dscale ? dscale[row0 + row] : 1.f;
                long long rb = ob + (long long)row * 64 + m;
                Out[rb]      = __float2bfloat16(acc0[r] * ds);
                Out[rb + 16] = __float2bfloat16(acc1[r] * ds);
                Out[rb + 32] = __float2bfloat16(acc2[r] * ds);
                Out[rb + 48] = __float2bfloat16(acc3[r] * ds);
            }
        }
    }
}

// ---------- fp32 VALU GEMM (fallback path only) ----------
template <int K, int XMODE>
__global__ __launch_bounds__(256)
void gemm_tile(const void* __restrict__ X, const void* __restrict__ W,
               const int* __restrict__ flags, const float* __restrict__ dscale,
               float* __restrict__ Out, int N) {
    __shared__ float lsW[K * 64];
    __shared__ float lsX[64 * K];
    int isf32 = flags[0];
    for (int i = threadIdx.x; i < K * 64; i += 256) lsW[i] = ld_f(W, i, isf32);
    int c  = threadIdx.x & 63;
    int wv = threadIdx.x >> 6;
    int ntiles = (N + 63) >> 6;
    for (int t = blockIdx.x; t < ntiles; t += gridDim.x) {
        int row0 = t << 6;
        int nrows = min(64, N - row0);
        int total = nrows * K;
        __syncthreads();
        if (XMODE == 1 || (XMODE == 0 && isf32)) {
            const float* Xb = (const float*)X + (long long)row0 * K;
            for (int i = threadIdx.x; i < total; i += 256) lsX[i] = Xb[i];
        } else {
            const unsigned short* Xb = (const unsigned short*)X + (long long)row0 * K;
            for (int i = threadIdx.x; i < total; i += 256) lsX[i] = bfbits((unsigned)Xb[i]);
        }
        __syncthreads();
        int rbase = wv * 16;
        float acc[16];
#pragma unroll
        for (int r = 0; r < 16; ++r) acc[r] = 0.f;
#pragma unroll 1
        for (int kc = 0; kc < K; kc += 8) {
            float w0 = lsW[(kc + 0) * 64 + c], w1 = lsW[(kc + 1) * 64 + c];
            float w2 = lsW[(kc + 2) * 64 + c], w3 = lsW[(kc + 3) * 64 + c];
            float w4 = lsW[(kc + 4) * 64 + c], w5 = lsW[(kc + 5) * 64 + c];
            float w6 = lsW[(kc + 6) * 64 + c], w7 = lsW[(kc + 7) * 64 + c];
#pragma unroll
            for (int r = 0; r < 16; ++r) {
                const float4* xp = (const float4*)&lsX[(rbase + r) * K + kc];
                float4 xa = xp[0], xb = xp[1];
                acc[r] += xa.x * w0 + xa.y * w1 + xa.z * w2 + xa.w * w3
                        + xb.x * w4 + xb.y * w5 + xb.z * w6 + xb.w * w7;
            }
        }
        long long ob = (long long)row0 * 64;
#pragma unroll
        for (int r = 0; r < 16; ++r) {
            int rr = rbase + r;
            if (rr < nrows) {
                float v = acc[r];
                if (dscale) v *= dscale[row0 + rr];
                Out[ob + (long long)rr * 64 + c] = v;
            }
        }
    }
}

// ---------- vectorized CSR gather, 4/8-deep pipelined, clamped loads ----------
// POOL=0: write bf16 Hout (optional out_scale).
// POOL=1: fused global-mean-pool. Block->node mapping is swizzled (bijective
// 200x125) so concurrently-resident blocks span ALL graphs (round-1 lesson).
template <int POOL>
__global__ __launch_bounds__(256)
void gather_v(const __hip_bfloat16* __restrict__ Hs,
              const int* __restrict__ rs,
              const int* __restrict__ re,
              const int* __restrict__ csr_src,
              const float* __restrict__ dinv,
              const void* bias, const int* __restrict__ flags,
              const float* __restrict__ out_scale,
              __hip_bfloat16* __restrict__ Hout,
              const void* batch, float* __restrict__ pooled,
              float* __restrict__ cntR, int N) {
    int isf32 = flags[0];
    int lane = threadIdx.x & 63;
    int e = lane >> 3;
    int f = lane & 7;
    int sub = threadIdx.x >> 6;
    int bid = blockIdx.x;
    int sb = (POOL == 1) ? ((bid % SWZA) * SWZB + bid / SWZA) : bid;
    int n = sb * 4 + sub;
    bool valid = n < N;
    if (POOL == 0 && !valid) return;

    int beg = 0, end = 0;
    if (valid) { beg = rs[n]; end = re[n]; }

    float acc[8];
#pragma unroll
    for (int j = 0; j < 8; ++j) acc[j] = 0.f;

    // 64 edges/iter with a wave-uniform half-guard: 4 row gathers in flight for
    // deg<=32 (54% of nodes), 8 for deg>32. Weights zero out clamped tails.
    for (int i = beg; i < end; i += 64) {
        int last = end - 1;
        int i0 = i + e;
        int s0 = csr_src[min(i0,      last)];
        int s1 = csr_src[min(i0 + 8,  last)];
        int s2 = csr_src[min(i0 + 16, last)];
        int s3 = csr_src[min(i0 + 24, last)];
        float w0 = (i0      < end) ? 1.f : 0.f;
        float w1 = (i0 + 8  < end) ? 1.f : 0.f;
        float w2 = (i0 + 16 < end) ? 1.f : 0.f;
        float w3 = (i0 + 24 < end) ? 1.f : 0.f;
        uint4 u0 = *((const uint4*)(Hs + ((long long)s0 << 6)) + f);
        uint4 u1 = *((const uint4*)(Hs + ((long long)s1 << 6)) + f);
        uint4 u2 = *((const uint4*)(Hs + ((long long)s2 << 6)) + f);
        uint4 u3 = *((const uint4*)(Hs + ((long long)s3 << 6)) + f);
        acc8w(acc, u0, w0);
        acc8w(acc, u1, w1);
        acc8w(acc, u2, w2);
        acc8w(acc, u3, w3);
        if (i + 32 < end) {                 // wave-uniform branch
            int i1 = i0 + 32;
            int s4 = csr_src[min(i1,      last)];
            int s5 = csr_src[min(i1 + 8,  last)];
            int s6 = csr_src[min(i1 + 16, last)];
            int s7 = csr_src[min(i1 + 24, last)];
            float w4 = (i1      < end) ? 1.f : 0.f;
            float w5 = (i1 + 8  < end) ? 1.f : 0.f;
            float w6 = (i1 + 16 < end) ? 1.f : 0.f;
            float w7 = (i1 + 24 < end) ? 1.f : 0.f;
            uint4 u4 = *((const uint4*)(Hs + ((long long)s4 << 6)) + f);
            uint4 u5 = *((const uint4*)(Hs + ((long long)s5 << 6)) + f);
            uint4 u6 = *((const uint4*)(Hs + ((long long)s6 << 6)) + f);
            uint4 u7 = *((const uint4*)(Hs + ((long long)s7 << 6)) + f);
            acc8w(acc, u4, w4);
            acc8w(acc, u5, w5);
            acc8w(acc, u6, w6);
            acc8w(acc, u7, w7);
        }
    }
#pragma unroll
    for (int j = 0; j < 8; ++j) {
        acc[j] += __shfl_xor(acc[j], 8);
        acc[j] += __shfl_xor(acc[j], 16);
        acc[j] += __shfl_xor(acc[j], 32);
    }
    float self[8];
#pragma unroll
    for (int j = 0; j < 8; ++j) self[j] = 0.f;
    if (valid) {
        const uint4* sp = (const uint4*)(Hs + ((long long)n << 6)) + f;
        uint4 su = *sp;
        self[0] = __uint_as_float(su.x << 16); self[1] = __uint_as_float(su.x & 0xffff0000u);
        self[2] = __uint_as_float(su.y << 16); self[3] = __uint_as_float(su.y & 0xffff0000u);
        self[4] = __uint_as_float(su.z << 16); self[5] = __uint_as_float(su.z & 0xffff0000u);
        self[6] = __uint_as_float(su.w << 16); self[7] = __uint_as_float(su.w & 0xffff0000u);
    }
    float dn = valid ? dinv[n] : 0.f;

    if constexpr (POOL == 0) {
        float osc = out_scale ? out_scale[n] : 1.f;
        if (e == 0) {
            unsigned short h[8];
#pragma unroll
            for (int j = 0; j < 8; ++j) {
                float v = (acc[j] + self[j]) * dn + ld_f(bias, 8 * f + j, isf32);
                float r = v > 0.f ? v : 0.f;
                h[j] = bf16b(r * osc);
            }
            uint4 o;
            o.x = (unsigned)h[0] | ((unsigned)h[1] << 16);
            o.y = (unsigned)h[2] | ((unsigned)h[3] << 16);
            o.z = (unsigned)h[4] | ((unsigned)h[5] << 16);
            o.w = (unsigned)h[6] | ((unsigned)h[7] << 16);
            *((uint4*)(Hout + ((long long)n << 6)) + f) = o;
        }
    } else {
        __shared__ float pbuf[4][64];
        __shared__ int pg[4];
        if (valid && e == 0) {
#pragma unroll
            for (int j = 0; j < 8; ++j) {
                float v = (acc[j] + self[j]) * dn + ld_f(bias, 8 * f + j, isf32);
                pbuf[sub][8 * f + j] = v > 0.f ? v : 0.f;
            }
        }
        if (lane == 0) {
            int g = -1;
            if (valid) {
                g = ld_idx(batch, n, flags[2]);
                if ((unsigned)g >= (unsigned)NG) g = -1;
            }
            pg[sub] = g;
        }
        __syncthreads();
        int c = threadIdx.x;
        if (c < 64) {
            // merge equal-graph runs: common case is 64 atomics per block,
            // spread across all graphs thanks to the block swizzle.
            float run = 0.f;
            int gcur2 = pg[0];
#pragma unroll
            for (int r = 0; r < 4; ++r) {
                int g = pg[r];
                if (g != gcur2) {
                    if (gcur2 >= 0 && run != 0.f) atomicAdd(&pooled[gcur2 * 64 + c], run);
                    run = 0.f;
                    gcur2 = g;
                }
                if (g >= 0) run += pbuf[r][c];
            }
            if (gcur2 >= 0 && run != 0.f) atomicAdd(&pooled[gcur2 * 64 + c], run);
        } else if (c == 64) {
            // run-merged node counts into a per-block replica (32 replicas)
            float* myc = cntR + (bid & (CNTREP - 1)) * NG;
            int run = 0;
            int gcur2 = pg[0];
#pragma unroll
            for (int r = 0; r < 4; ++r) {
                int g = pg[r];
                if (g != gcur2) {
                    if (gcur2 >= 0 && run) atomicAdd(&myc[gcur2], (float)run);
                    run = 0;
                    gcur2 = g;
                }
                if (g >= 0) run++;
            }
            if (gcur2 >= 0 && run) atomicAdd(&myc[gcur2], (float)run);
        }
    }
}

// ---------- final (cnt held in nrep replicas) ----------
__global__ void final_kernel(const float* __restrict__ pooled, const float* __restrict__ cntR,
                             int nrep, const void* lw, const void* lb,
                             const int* __restrict__ flags, void* out) {
    int isf32 = flags[0];
    int g = threadIdx.x;
    if (g >= NG) return;
    float cv = 0.f;
    for (int r = 0; r < nrep; ++r) cv += cntR[r * NG + g];
    float inv = 1.0f / fmaxf(cv, 1.0f);
    float logits[10];
    for (int c = 0; c < 10; ++c) logits[c] = ld_f(lb, c, isf32);
    for (int k = 0; k < 64; ++k) {
        float m = pooled[g * 64 + k] * inv;
        for (int c = 0; c < 10; ++c)
            logits[c] += m * ld_f(lw, k * 10 + c, isf32);
    }
    float mx = logits[0];
    for (int c = 1; c < 10; ++c) mx = fmaxf(mx, logits[c]);
    float se = 0.f;
    for (int c = 0; c < 10; ++c) se += __expf(logits[c] - mx);
    float lse = mx + __logf(se);
    if (isf32) {
        float* o = (float*)out;
        for (int c = 0; c < 10; ++c) o[g * 10 + c] = logits[c] - lse;
    } else {
        __hip_bfloat16* o = (__hip_bfloat16*)out;
        for (int c = 0; c < 10; ++c) o[g * 10 + c] = __float2bfloat16(logits[c] - lse);
    }
}

// ---------- fallback pipeline kernels (atomic scatter, fp32) ----------
__global__ void count_kernel(const void* ei, const int* __restrict__ flags,
                             int* __restrict__ deg, int E) {
    int is64 = flags[1];
    int i = blockIdx.x * blockDim.x + threadIdx.x;
    int stride = gridDim.x * blockDim.x;
    for (; i < E; i += stride) {
        int d = ld_idx(ei, (long long)E + i, is64);
        if ((unsigned)d < (unsigned)NNODES) atomicAdd(&deg[d], 1);
    }
}

__global__ void dinv_kernel(const int* __restrict__ deg, float* __restrict__ dinv, int N) {
    int i = blockIdx.x * blockDim.x + threadIdx.x;
    if (i < N) dinv[i] = rsqrtf((float)deg[i] + 1.0f);
}

__global__ void scatter_kernel(const float* __restrict__ H, const void* ei,
                               const int* __restrict__ flags,
                               const float* __restrict__ dinv,
                               float* __restrict__ agg, int E) {
    int is64 = flags[1];
    int lane = threadIdx.x & 63;
    int e = blockIdx.x * 4 + (threadIdx.x >> 6);
    if (e >= E) return;
    int s = ld_idx(ei, e, is64);
    int d = ld_idx(ei, (long long)E + e, is64);
    if ((unsigned)s >= (unsigned)NNODES || (unsigned)d >= (unsigned)NNODES) return;
    float nrm = dinv[s] * dinv[d];
    float v = H[(long long)s * 64 + lane] * nrm;
    atomicAdd(&agg[(long long)d * 64 + lane], v);
}

__global__ void relu_bias_kernel(float* __restrict__ H, const float* __restrict__ agg,
                                 const float* __restrict__ dinv, const void* b,
                                 const int* __restrict__ flags, int N) {
    int isf32 = flags[0];
    long long idx = (long long)blockIdx.x * blockDim.x + threadIdx.x;
    if (idx >= (long long)N * 64) return;
    int n = (int)(idx >> 6);
    int c = (int)(idx & 63);
    float dv = dinv[n];
    float v = agg[idx] + H[idx] * dv * dv + ld_f(b, c, isf32);
    H[idx] = v > 0.f ? v : 0.f;
}

__global__ void pool_fb_kernel(const float* __restrict__ agg, const float* __restrict__ Hg,
                               const float* __restrict__ dinv, const void* b,
                               const void* batch, const int* __restrict__ flags,
                               float* __restrict__ pooled, float* __restrict__ cnt, int N) {
    __shared__ float part[NG * 64];
    __shared__ float scnt[NG];
    int isf32 = flags[0];
    int b64   = flags[2];
    int tid = threadIdx.x;
    for (int i = tid; i < NG * 64; i += blockDim.x) part[i] = 0.f;
    if (tid < NG) scnt[tid] = 0.f;
    __syncthreads();
    int c = tid & 63;
    int sub = tid >> 6;
    float bc = ld_f(b, c, isf32);
    for (int n = blockIdx.x * 4 + sub; n < N; n += gridDim.x * 4) {
        int g = ld_idx(batch, n, b64);
        if ((unsigned)g >= (unsigned)NG) continue;
        float dv = dinv[n];
        float v = agg[(long long)n * 64 + c] + Hg[(long long)n * 64 + c] * dv * dv + bc;
        v = v > 0.f ? v : 0.f;
        atomicAdd(&part[g * 64 + c], v);
        if (c == 0) atomicAdd(&scnt[g], 1.0f);
    }
    __syncthreads();
    for (int i = tid; i < NG * 64; i += blockDim.x) {
        float v = part[i];
        if (v != 0.f) atomicAdd(&pooled[i], v);
    }
    if (tid < NG && scnt[tid] != 0.f) atomicAdd(&cnt[tid], scnt[tid]);
}

__global__ void zero_out_kernel(unsigned short* out, int n16) {
    int i = blockIdx.x * blockDim.x + threadIdx.x;
    if (i < n16) out[i] = 0;
}

extern "C" void kernel_launch(void* const* d_in, const int* in_sizes, int n_in,
                              void* d_out, int out_size, void* d_ws, size_t ws_size,
                              hipStream_t stream) {
    const void* x   = d_in[0];
    const void* ei  = d_in[1];   // [2, E] flat: src then dst
    const void* bat = d_in[2];
    const void* W1  = d_in[3];
    const void* b1  = d_in[4];
    const void* W2  = d_in[5];
    const void* b2  = d_in[6];
    const void* lw  = d_in[7];
    const void* lb  = d_in[8];

    const int N = NNODES, E = NEDGES;
    int* ws = (int*)d_ws;
    const int NT = (N + 63) / 64;    // gemm tiles

    // ---- CSR-path layout (words). staging aliases bufA (dead before GEMM1). ----
    const long long o_flags = 0;                          // 16
    const long long o_re    = 16;                         // N (per-node CSR end)
    const long long o_dinv  = 16 + (long long)N;          // N
    const long long o_rs    = 16 + 2LL * N;               // N+1 (per-node CSR start)
    const long long o_gcur  = 300032;                     // 256 bucket cursors
    const long long o_cntR  = 300288;                     // CNTREP*NG = 2048
    const long long o_pool  = 350272;                     // NG*64
    const long long o_cnt   = o_pool + NG * 64;           // NG (fallback cnt)
    const long long o_csr   = 354432;                     // E words (COMPACT csr)
    const long long o_bufA  = o_csr + E;                  // N*64 words (bf16 uses half)
    const long long o_bufB  = o_bufA + (long long)N * 64; // N*64 words
    const size_t need_csr = (size_t)(o_bufB + (long long)N * 64) * 4;   // ~65.4 MB

    // staging (bucket-gapped, CAP*NBUCK = 4,014,080 words) aliases bufA+bufB
    // (12.8M words) -- both dead until GEMM1 runs.

    // ---- fallback layout ----
    const size_t need_fb = (size_t)(204800 + 2LL * N * 64) * 4;

    if (ws_size >= need_csr) {
        int*      flags   = ws + o_flags;
        int*      re      = ws + o_re;
        float*    dinv    = (float*)(ws + o_dinv);
        int*      rs      = ws + o_rs;
        int*      gcur    = ws + o_gcur;
        float*    cntR    = (float*)(ws + o_cntR);
        float*    pooled  = (float*)(ws + o_pool);
        int*      csr     = ws + o_csr;
        unsigned* staging = (unsigned*)(ws + o_bufA);     // alias: dead before GEMM1
        __hip_bfloat16* hA = (__hip_bfloat16*)(ws + o_bufA);
        __hip_bfloat16* hB = (__hip_bfloat16*)(ws + o_bufB);

        // detect dtypes + init cursors/pooled/cnt (no memset launches)
        detect_kernel<<<1, 256, 0, stream>>>(x, ei, bat, flags, gcur, pooled, cntR);

        // 2-kernel CSR build: fused count+reserve+partition, then per-bucket fill
        binA_fused<<<PB, 256, 0, stream>>>(ei, flags, gcur, staging, E);
        binB_all<<<NBUCK, 256, 0, stream>>>(staging, gcur, rs, re, dinv, csr);

        // layer 1: MFMA gemm1 -> bf16 dinv*(x@W1); gather1 -> bf16 dinv*relu(...)
        gemm_mfma<128, 0><<<NT, 256, 0, stream>>>(x, W1, flags, dinv, hA, N);
        gather_v<0><<<NBLK4, 256, 0, stream>>>(hA, rs, re, csr, dinv, b1, flags, dinv, hB,
                                               nullptr, nullptr, nullptr, N);
        // layer 2: MFMA gemm2 bf16 -> bf16; gather2 fused with global mean pool
        gemm_mfma<64, 2><<<NT, 256, 0, stream>>>(hB, W2, flags, nullptr, hA, N);
        gather_v<1><<<NBLK4, 256, 0, stream>>>(hA, rs, re, csr, dinv, b2, flags, nullptr,
                                               nullptr, bat, pooled, cntR, N);

        final_kernel<<<1, 64, 0, stream>>>(pooled, cntR, CNTREP, lw, lb, flags, d_out);
    } else if (ws_size >= need_fb) {
        int*   flags  = ws;
        int*   deg    = ws + 16;
        float* dinv   = (float*)(ws + 16 + N);
        float* pooled = (float*)(ws + 16 + 2LL * N);
        float* cnt    = pooled + NG * 64;
        float* bufA   = (float*)(ws + 204800);
        float* bufB   = bufA + (long long)N * 64;

        detect_kernel<<<1, 256, 0, stream>>>(x, ei, bat, flags, nullptr, nullptr, nullptr);
        hipMemsetAsync(deg, 0, N * sizeof(int), stream);
        hipMemsetAsync(pooled, 0, (NG * 64 + NG) * sizeof(float), stream);

        count_kernel<<<2048, 256, 0, stream>>>(ei, flags, deg, E);
        dinv_kernel<<<(N + 255) / 256, 256, 0, stream>>>(deg, dinv, N);

        gemm_tile<128, 0><<<NT, 256, 0, stream>>>(x, W1, flags, nullptr, bufA, N);
        hipMemsetAsync(bufB, 0, (size_t)N * 64 * sizeof(float), stream);
        scatter_kernel<<<(E + 3) / 4, 256, 0, stream>>>(bufA, ei, flags, dinv, bufB, E);
        relu_bias_kernel<<<((long long)N * 64 + 255) / 256, 256, 0, stream>>>(bufA, bufB, dinv, b1, flags, N);

        gemm_tile<64, 1><<<NT, 256, 0, stream>>>(bufA, W2, flags, nullptr, bufB, N);
        hipMemsetAsync(bufA, 0, (size_t)N * 64 * sizeof(float), stream);
        scatter_kernel<<<(E + 3) / 4, 256, 0, stream>>>(bufB, ei, flags, dinv, bufA, E);

        pool_fb_kernel<<<512, 256, 0, stream>>>(bufA, bufB, dinv, b2, bat, flags, pooled, cnt, N);
        final_kernel<<<1, 64, 0, stream>>>(pooled, cnt, 1, lw, lb, flags, d_out);
    } else {
        zero_out_kernel<<<(out_size * 2 + 255) / 256, 256, 0, stream>>>(
            (unsigned short*)d_out, out_size);
    }
}